// Round 2
// baseline (217.696 us; speedup 1.0000x reference)
//
#include <hip/hip_runtime.h>

typedef unsigned short u16;
typedef unsigned int   u32;
typedef __bf16 bf16x8 __attribute__((ext_vector_type(8)));
typedef float  f32x4  __attribute__((ext_vector_type(4)));

// Geometry (fixed): b=32, h=w=56, C=192, NH=6, hd=32, WS=7, shift=3
// 2048 windows, 49 tokens (padded to 64). One block (4 waves) per window.

__device__ __forceinline__ u16 f2b(float f){
  u32 u = __builtin_bit_cast(u32, f);
  u += 0x7FFFu + ((u >> 16) & 1u);
  return (u16)(u >> 16);
}

__global__ __launch_bounds__(256) void prep_kernel(const float* __restrict__ qkvw,
                                                   const float* __restrict__ projw,
                                                   u16* __restrict__ wq, u16* __restrict__ wp){
  const int i = blockIdx.x * 256 + threadIdx.x;
  if (i < 576*192) wq[i] = f2b(qkvw[i]);
  if (i < 192*192) wp[i] = f2b(projw[i]);
}

__device__ __forceinline__ int coords_fn(int t){ return (t/7)*13 + (t%7); }
__device__ __forceinline__ int code_fn(int t, int wy, int wx){
  const int ty = t/7, tx = t%7;
  const int hp = wy*7 + ty, wp = wx*7 + tx;
  const int rh = (hp < 49) ? 0 : ((hp < 53) ? 1 : 2);
  const int rw = (wp < 49) ? 0 : ((wp < 53) ? 1 : 2);
  return rh*3 + rw;
}

__global__ __launch_bounds__(256, 1) void fused_kernel(const float* __restrict__ x,
    const u16* __restrict__ wq, const float* __restrict__ qb,
    const u16* __restrict__ wp, const float* __restrict__ pb,
    const float* __restrict__ rpb, float* __restrict__ out)
{
  __shared__ u16 XA[64][200];   // phase 1-2: x tile; phase 3-4: attention output (overlay)
  __shared__ u16 qs[64][200];   // q, natural [tok][192]
  __shared__ u16 kk[64][200];   // k, natural [tok][192]
  __shared__ u16 vTs[192][72];  // v transposed [ch][tok], +8 pad
  __shared__ u16 Ps[4][16][72]; // per-wave P tile

  const int wi = blockIdx.x;
  const int bb = wi >> 6, wy = (wi >> 3) & 7, wx = wi & 7;
  const int tid = threadIdx.x;
  const int wave = tid >> 6, lane = tid & 63;
  const int g = lane >> 4, r = lane & 15;
  const f32x4 z4 = {0.f, 0.f, 0.f, 0.f};

  // ---- phase 1: roll + window gather, fp32 -> bf16, rows >=49 zeroed ----
  for (int it = tid; it < 64*48; it += 256){
    const int row = it / 48, c4 = (it % 48) * 4;
    u32 p0 = 0, p1 = 0;
    if (row < 49){
      const int ty = row / 7, tx = row % 7;
      int sh = wy*7 + ty + 3; if (sh >= 56) sh -= 56;
      int sw = wx*7 + tx + 3; if (sw >= 56) sw -= 56;
      const float4 f = *reinterpret_cast<const float4*>(x + (size_t)(((bb*56 + sh)*56 + sw))*192 + c4);
      p0 = (u32)f2b(f.x) | ((u32)f2b(f.y) << 16);
      p1 = (u32)f2b(f.z) | ((u32)f2b(f.w) << 16);
    }
    u32* dst = reinterpret_cast<u32*>(&XA[row][c4]);
    dst[0] = p0; dst[1] = p1;
  }
  __syncthreads();

  // ---- phase 2: QKV GEMM (A-frags hoisted; no barriers inside) ----
  {
    bf16x8 af[6][4];
    #pragma unroll
    for (int ks = 0; ks < 6; ++ks)
      #pragma unroll
      for (int mt = 0; mt < 4; ++mt)
        af[ks][mt] = *reinterpret_cast<const bf16x8*>(&XA[mt*16 + r][ks*32 + 8*g]);

    // q (nc 0..2) and k (nc 3..5) chunks
    #pragma unroll
    for (int nc = 0; nc < 6; ++nc){
      const int nbase = nc*64 + wave*16;
      bf16x8 bf_[6];
      #pragma unroll
      for (int ks = 0; ks < 6; ++ks)
        bf_[ks] = *reinterpret_cast<const bf16x8*>(wq + (size_t)(nbase + r)*192 + ks*32 + 8*g);
      f32x4 acc[4] = {z4, z4, z4, z4};
      #pragma unroll
      for (int ks = 0; ks < 6; ++ks)
        #pragma unroll
        for (int mt = 0; mt < 4; ++mt)
          acc[mt] = __builtin_amdgcn_mfma_f32_16x16x32_bf16(af[ks][mt], bf_[ks], acc[mt], 0, 0, 0);
      const float bias = qb[nbase + r];
      const float mul = (nc < 3) ? 0.17677669529663687f : 1.0f;
      #pragma unroll
      for (int mt = 0; mt < 4; ++mt)
        #pragma unroll
        for (int jj = 0; jj < 4; ++jj){
          const int row = mt*16 + 4*g + jj;
          const u16 val = f2b((acc[mt][jj] + bias) * mul);
          if (nc < 3) qs[row][nbase + r]       = val;
          else        kk[row][nbase - 192 + r] = val;
        }
    }
    // v chunks (nc 6..8): transpose into vTs with packed 8B stores
    #pragma unroll
    for (int nc = 0; nc < 3; ++nc){
      const int nbase = 384 + nc*64 + wave*16;
      bf16x8 bf_[6];
      #pragma unroll
      for (int ks = 0; ks < 6; ++ks)
        bf_[ks] = *reinterpret_cast<const bf16x8*>(wq + (size_t)(nbase + r)*192 + ks*32 + 8*g);
      f32x4 acc[4] = {z4, z4, z4, z4};
      #pragma unroll
      for (int ks = 0; ks < 6; ++ks)
        #pragma unroll
        for (int mt = 0; mt < 4; ++mt)
          acc[mt] = __builtin_amdgcn_mfma_f32_16x16x32_bf16(af[ks][mt], bf_[ks], acc[mt], 0, 0, 0);
      const float bias = qb[nbase + r];
      const int ch = nbase + r - 384;          // 0..191 = head*32 + d
      #pragma unroll
      for (int mt = 0; mt < 4; ++mt){
        const u16 a0 = f2b(acc[mt][0] + bias);
        const u16 a1 = f2b(acc[mt][1] + bias);
        const u16 a2 = f2b(acc[mt][2] + bias);
        const u16 a3 = f2b(acc[mt][3] + bias);
        u32* dst = reinterpret_cast<u32*>(&vTs[ch][mt*16 + 4*g]);
        dst[0] = (u32)a0 | ((u32)a1 << 16);
        dst[1] = (u32)a2 | ((u32)a3 << 16);
      }
    }
  }
  __syncthreads();

  // ---- phase 3: attention; wave w owns query rows [16w, 16w+16) ----
  {
    // column (key) metadata, head-independent
    int cj[4], codej[4]; bool jvalid[4];
    #pragma unroll
    for (int nt = 0; nt < 4; ++nt){
      const int j = nt*16 + r;
      jvalid[nt] = (j < 49);
      const int jc = jvalid[nt] ? (48 - j) : 0;
      cj[nt] = coords_fn(jc);
      codej[nt] = jvalid[nt] ? code_fn(j, wy, wx) : 0;
    }
    // row metadata
    int ci_[4], codei_[4];
    #pragma unroll
    for (int jj = 0; jj < 4; ++jj){
      int i = wave*16 + 4*g + jj; if (i > 48) i = 48;
      ci_[jj] = coords_fn(i);
      codei_[jj] = code_fn(i, wy, wx);
    }

    for (int h = 0; h < 6; ++h){
      const bf16x8 aq = *reinterpret_cast<const bf16x8*>(&qs[wave*16 + r][h*32 + 8*g]);
      f32x4 s[4] = {z4, z4, z4, z4};
      #pragma unroll
      for (int nt = 0; nt < 4; ++nt){
        const bf16x8 bk = *reinterpret_cast<const bf16x8*>(&kk[nt*16 + r][h*32 + 8*g]);
        s[nt] = __builtin_amdgcn_mfma_f32_16x16x32_bf16(aq, bk, s[nt], 0, 0, 0);
      }
      // bias + shift-mask + row max
      float mx[4];
      #pragma unroll
      for (int jj = 0; jj < 4; ++jj){
        float m_ = -1e30f;
        #pragma unroll
        for (int nt = 0; nt < 4; ++nt){
          float lg = -1e30f;
          if (jvalid[nt]){
            lg = s[nt][jj] + rpb[(ci_[jj] + cj[nt])*6 + h];
            if (codei_[jj] != codej[nt]) lg -= 100.0f;
          }
          s[nt][jj] = lg;
          m_ = fmaxf(m_, lg);
        }
        mx[jj] = m_;
      }
      #pragma unroll
      for (int jj = 0; jj < 4; ++jj){
        float m_ = mx[jj];
        m_ = fmaxf(m_, __shfl_xor(m_, 1));
        m_ = fmaxf(m_, __shfl_xor(m_, 2));
        m_ = fmaxf(m_, __shfl_xor(m_, 4));
        m_ = fmaxf(m_, __shfl_xor(m_, 8));
        mx[jj] = m_;
      }
      float rs_[4];
      #pragma unroll
      for (int jj = 0; jj < 4; ++jj){
        float sum = 0.f;
        #pragma unroll
        for (int nt = 0; nt < 4; ++nt){
          const float p = __expf(s[nt][jj] - mx[jj]);
          s[nt][jj] = p;
          sum += p;
        }
        sum += __shfl_xor(sum, 1);
        sum += __shfl_xor(sum, 2);
        sum += __shfl_xor(sum, 4);
        sum += __shfl_xor(sum, 8);
        rs_[jj] = 1.0f / sum;
      }
      #pragma unroll
      for (int nt = 0; nt < 4; ++nt)
        #pragma unroll
        for (int jj = 0; jj < 4; ++jj)
          Ps[wave][4*g + jj][nt*16 + r] = f2b(s[nt][jj] * rs_[jj]);

      // PV (wave-local P: compiler orders LDS write->read via lgkmcnt)
      f32x4 o[2] = {z4, z4};
      #pragma unroll
      for (int k2 = 0; k2 < 2; ++k2){
        const bf16x8 ap = *reinterpret_cast<const bf16x8*>(&Ps[wave][r][k2*32 + 8*g]);
        #pragma unroll
        for (int nt = 0; nt < 2; ++nt){
          const bf16x8 bv = *reinterpret_cast<const bf16x8*>(&vTs[h*32 + nt*16 + r][k2*32 + 8*g]);
          o[nt] = __builtin_amdgcn_mfma_f32_16x16x32_bf16(ap, bv, o[nt], 0, 0, 0);
        }
      }
      #pragma unroll
      for (int nt = 0; nt < 2; ++nt)
        #pragma unroll
        for (int jj = 0; jj < 4; ++jj)
          XA[wave*16 + 4*g + jj][h*32 + nt*16 + r] = f2b(o[nt][jj]);
    }
  }
  __syncthreads();

  // ---- phase 4: proj GEMM + window-reverse + roll-back ----
  {
    bf16x8 a2[6][4];
    #pragma unroll
    for (int ks = 0; ks < 6; ++ks)
      #pragma unroll
      for (int mt = 0; mt < 4; ++mt)
        a2[ks][mt] = *reinterpret_cast<const bf16x8*>(&XA[mt*16 + r][ks*32 + 8*g]);

    f32x4 acc[4][3];
    #pragma unroll
    for (int mt = 0; mt < 4; ++mt){ acc[mt][0] = z4; acc[mt][1] = z4; acc[mt][2] = z4; }
    #pragma unroll
    for (int nt = 0; nt < 3; ++nt){
      const int nb = wave*48 + nt*16;
      #pragma unroll
      for (int ks = 0; ks < 6; ++ks){
        const bf16x8 bw = *reinterpret_cast<const bf16x8*>(wp + (size_t)(nb + r)*192 + ks*32 + 8*g);
        #pragma unroll
        for (int mt = 0; mt < 4; ++mt)
          acc[mt][nt] = __builtin_amdgcn_mfma_f32_16x16x32_bf16(a2[ks][mt], bw, acc[mt][nt], 0, 0, 0);
      }
    }
    #pragma unroll
    for (int nt = 0; nt < 3; ++nt){
      const int n = wave*48 + nt*16 + r;
      const float bias = pb[n];
      #pragma unroll
      for (int mt = 0; mt < 4; ++mt)
        #pragma unroll
        for (int jj = 0; jj < 4; ++jj){
          const int tok = mt*16 + 4*g + jj;
          if (tok < 49){
            const int ty = tok/7, tx = tok%7;
            int dh = wy*7 + ty + 3; if (dh >= 56) dh -= 56;
            int dw = wx*7 + tx + 3; if (dw >= 56) dw -= 56;
            out[(size_t)((bb*56 + dh)*56 + dw)*192 + n] = acc[mt][nt][jj] + bias;
          }
        }
    }
  }
}

extern "C" void kernel_launch(void* const* d_in, const int* in_sizes, int n_in,
                              void* d_out, int out_size, void* d_ws, size_t ws_size,
                              hipStream_t stream) {
  const float* x     = (const float*)d_in[0];
  const float* rpb   = (const float*)d_in[1];
  const float* qkvw  = (const float*)d_in[2];
  const float* qkvb  = (const float*)d_in[3];
  const float* projw = (const float*)d_in[4];
  const float* projb = (const float*)d_in[5];
  float* out = (float*)d_out;

  char* ws = (char*)d_ws;
  u16* wq  = (u16*)(ws);            // bf16 [576][192]
  u16* wpj = (u16*)(ws + 221184);   // bf16 [192][192]

  prep_kernel <<<432, 256, 0, stream>>>(qkvw, projw, wq, wpj);
  fused_kernel<<<2048, 256, 0, stream>>>(x, wq, qkvb, wpj, projb, rpb, out);
}

// Round 3
// 199.171 us; speedup vs baseline: 1.0930x; 1.0930x over previous
//
#include <hip/hip_runtime.h>

typedef unsigned short u16;
typedef unsigned int   u32;
typedef __bf16 bf16x8 __attribute__((ext_vector_type(8)));
typedef float  f32x4  __attribute__((ext_vector_type(4)));

// Geometry (fixed): b=32, h=w=56, C=192, NH=6, hd=32, WS=7, shift=3
// 2048 windows, 49 tokens (padded to 64). One block (4 waves) per window.
// Per-head loop keeps LDS at ~48.5 KB -> 3 blocks/CU (3 waves/SIMD).

__device__ __forceinline__ u16 f2b(float f){
  u32 u = __builtin_bit_cast(u32, f);
  u += 0x7FFFu + ((u >> 16) & 1u);
  return (u16)(u >> 16);
}

__global__ __launch_bounds__(256) void prep_kernel(const float* __restrict__ qkvw,
                                                   const float* __restrict__ projw,
                                                   u16* __restrict__ wq, u16* __restrict__ wp){
  const int i = blockIdx.x * 256 + threadIdx.x;
  if (i < 576*192) wq[i] = f2b(qkvw[i]);
  if (i < 192*192) wp[i] = f2b(projw[i]);
}

__device__ __forceinline__ int coords_fn(int t){ return (t/7)*13 + (t%7); }
__device__ __forceinline__ int code_fn(int t, int wy, int wx){
  const int ty = t/7, tx = t%7;
  const int hp = wy*7 + ty, wp = wx*7 + tx;
  const int rh = (hp < 49) ? 0 : ((hp < 53) ? 1 : 2);
  const int rw = (wp < 49) ? 0 : ((wp < 53) ? 1 : 2);
  return rh*3 + rw;
}

__global__ __launch_bounds__(256, 3) void fused_kernel(const float* __restrict__ x,
    const u16* __restrict__ wq, const float* __restrict__ qb,
    const u16* __restrict__ wp, const float* __restrict__ pb,
    const float* __restrict__ rpb, float* __restrict__ out)
{
  __shared__ u16 XA[64][200];    // phase 1: x tile; after af-hoist: AO overlay
  __shared__ u16 qsh[64][40];    // per-head q [tok][32+8]
  __shared__ u16 ksh[64][40];    // per-head k [tok][32+8]
  __shared__ u16 vTsh[32][72];   // per-head v^T [d][tok+8]
  __shared__ u16 Ps[4][16][72];  // per-wave P tile

  const int wi = blockIdx.x;
  const int bb = wi >> 6, wy = (wi >> 3) & 7, wx = wi & 7;
  const int tid = threadIdx.x;
  const int wave = tid >> 6, lane = tid & 63;
  const int g = lane >> 4, r = lane & 15;
  const int wm = wave >> 1, wn = wave & 1;   // QKV GEMM: 2x2 wave grid
  const f32x4 z4 = {0.f, 0.f, 0.f, 0.f};

  // ---- phase 1: roll + window gather, fp32 -> bf16, rows >=49 zeroed ----
  for (int it = tid; it < 64*48; it += 256){
    const int row = it / 48, c4 = (it % 48) * 4;
    u32 p0 = 0, p1 = 0;
    if (row < 49){
      const int ty = row / 7, tx = row % 7;
      int sh = wy*7 + ty + 3; if (sh >= 56) sh -= 56;
      int sw = wx*7 + tx + 3; if (sw >= 56) sw -= 56;
      const float4 f = *reinterpret_cast<const float4*>(x + (size_t)(((bb*56 + sh)*56 + sw))*192 + c4);
      p0 = (u32)f2b(f.x) | ((u32)f2b(f.y) << 16);
      p1 = (u32)f2b(f.z) | ((u32)f2b(f.w) << 16);
    }
    u32* dst = reinterpret_cast<u32*>(&XA[row][c4]);
    dst[0] = p0; dst[1] = p1;
  }
  __syncthreads();

  // ---- hoist X fragments to registers: rows wm*32 + mt*16 + r ----
  bf16x8 af[6][2];
  #pragma unroll
  for (int ks = 0; ks < 6; ++ks)
    #pragma unroll
    for (int mt = 0; mt < 2; ++mt)
      af[ks][mt] = *reinterpret_cast<const bf16x8*>(&XA[wm*32 + mt*16 + r][ks*32 + 8*g]);

  // ---- attention metadata (head-independent) ----
  int cj[4], codej[4]; bool jvalid[4];
  #pragma unroll
  for (int nt = 0; nt < 4; ++nt){
    const int j = nt*16 + r;
    jvalid[nt] = (j < 49);
    const int jc = jvalid[nt] ? (48 - j) : 0;
    cj[nt] = coords_fn(jc);
    codej[nt] = jvalid[nt] ? code_fn(j, wy, wx) : 0;
  }
  int ci_[4], codei_[4];
  #pragma unroll
  for (int jj = 0; jj < 4; ++jj){
    int i = wave*16 + 4*g + jj; if (i > 48) i = 48;
    ci_[jj] = coords_fn(i);
    codei_[jj] = code_fn(i, wy, wx);
  }

  // ---- per-head loop: QKV GEMM (head slice) -> attention -> AO ----
  for (int h = 0; h < 6; ++h){
    // QKV: out 64x96 (q|k|v), wave (wm,wn): rows wm*32+{0,16}, cols wn*48+{0,16,32}
    f32x4 acc[2][3];
    float biasv[3];
    #pragma unroll
    for (int mt = 0; mt < 2; ++mt)
      #pragma unroll
      for (int nt = 0; nt < 3; ++nt)
        acc[mt][nt] = z4;
    #pragma unroll
    for (int nt = 0; nt < 3; ++nt){
      const int base = wn*48 + nt*16;        // {0,16,32} or {48,64,80}
      const int seg = base >> 5;             // 0=q 1=k 2=v
      const int wrow = seg*192 + h*32 + (base - seg*32) + r;
      bf16x8 bf_[6];
      #pragma unroll
      for (int ks = 0; ks < 6; ++ks)
        bf_[ks] = *reinterpret_cast<const bf16x8*>(wq + (size_t)wrow*192 + ks*32 + 8*g);
      biasv[nt] = qb[wrow];
      #pragma unroll
      for (int ks = 0; ks < 6; ++ks)
        #pragma unroll
        for (int mt = 0; mt < 2; ++mt)
          acc[mt][nt] = __builtin_amdgcn_mfma_f32_16x16x32_bf16(af[ks][mt], bf_[ks], acc[mt][nt], 0, 0, 0);
    }
    // epilogue: q,k natural; v transposed
    #pragma unroll
    for (int nt = 0; nt < 3; ++nt){
      const int base = wn*48 + nt*16;
      const int seg = base >> 5;
      if (seg == 0){
        #pragma unroll
        for (int mt = 0; mt < 2; ++mt)
          #pragma unroll
          for (int jj = 0; jj < 4; ++jj)
            qsh[wm*32 + mt*16 + 4*g + jj][base + r] =
              f2b((acc[mt][nt][jj] + biasv[nt]) * 0.17677669529663687f);
      } else if (seg == 1){
        #pragma unroll
        for (int mt = 0; mt < 2; ++mt)
          #pragma unroll
          for (int jj = 0; jj < 4; ++jj)
            ksh[wm*32 + mt*16 + 4*g + jj][base - 32 + r] = f2b(acc[mt][nt][jj] + biasv[nt]);
      } else {
        const int d = base - 64 + r;
        #pragma unroll
        for (int mt = 0; mt < 2; ++mt){
          const u16 a0 = f2b(acc[mt][nt][0] + biasv[nt]);
          const u16 a1 = f2b(acc[mt][nt][1] + biasv[nt]);
          const u16 a2 = f2b(acc[mt][nt][2] + biasv[nt]);
          const u16 a3 = f2b(acc[mt][nt][3] + biasv[nt]);
          u32* dst = reinterpret_cast<u32*>(&vTsh[d][wm*32 + mt*16 + 4*g]);
          dst[0] = (u32)a0 | ((u32)a1 << 16);
          dst[1] = (u32)a2 | ((u32)a3 << 16);
        }
      }
    }
    __syncthreads();

    // attention head h: wave owns query rows [wave*16, wave*16+16)
    {
      const bf16x8 aq = *reinterpret_cast<const bf16x8*>(&qsh[wave*16 + r][8*g]);
      f32x4 s[4] = {z4, z4, z4, z4};
      #pragma unroll
      for (int nt = 0; nt < 4; ++nt){
        const bf16x8 bk = *reinterpret_cast<const bf16x8*>(&ksh[nt*16 + r][8*g]);
        s[nt] = __builtin_amdgcn_mfma_f32_16x16x32_bf16(aq, bk, s[nt], 0, 0, 0);
      }
      float mx[4];
      #pragma unroll
      for (int jj = 0; jj < 4; ++jj){
        float m_ = -1e30f;
        #pragma unroll
        for (int nt = 0; nt < 4; ++nt){
          float lg = -1e30f;
          if (jvalid[nt]){
            lg = s[nt][jj] + rpb[(ci_[jj] + cj[nt])*6 + h];
            if (codei_[jj] != codej[nt]) lg -= 100.0f;
          }
          s[nt][jj] = lg;
          m_ = fmaxf(m_, lg);
        }
        mx[jj] = m_;
      }
      #pragma unroll
      for (int jj = 0; jj < 4; ++jj){
        float m_ = mx[jj];
        m_ = fmaxf(m_, __shfl_xor(m_, 1));
        m_ = fmaxf(m_, __shfl_xor(m_, 2));
        m_ = fmaxf(m_, __shfl_xor(m_, 4));
        m_ = fmaxf(m_, __shfl_xor(m_, 8));
        mx[jj] = m_;
      }
      float rs_[4];
      #pragma unroll
      for (int jj = 0; jj < 4; ++jj){
        float sum = 0.f;
        #pragma unroll
        for (int nt = 0; nt < 4; ++nt){
          const float p = __expf(s[nt][jj] - mx[jj]);
          s[nt][jj] = p;
          sum += p;
        }
        sum += __shfl_xor(sum, 1);
        sum += __shfl_xor(sum, 2);
        sum += __shfl_xor(sum, 4);
        sum += __shfl_xor(sum, 8);
        rs_[jj] = 1.0f / sum;
      }
      #pragma unroll
      for (int nt = 0; nt < 4; ++nt)
        #pragma unroll
        for (int jj = 0; jj < 4; ++jj)
          Ps[wave][4*g + jj][nt*16 + r] = f2b(s[nt][jj] * rs_[jj]);

      // PV: O(16x32) = P(16x64) @ v(64x32)
      f32x4 o[2] = {z4, z4};
      #pragma unroll
      for (int k2 = 0; k2 < 2; ++k2){
        const bf16x8 ap = *reinterpret_cast<const bf16x8*>(&Ps[wave][r][k2*32 + 8*g]);
        #pragma unroll
        for (int nt = 0; nt < 2; ++nt){
          const bf16x8 bv = *reinterpret_cast<const bf16x8*>(&vTsh[nt*16 + r][k2*32 + 8*g]);
          o[nt] = __builtin_amdgcn_mfma_f32_16x16x32_bf16(ap, bv, o[nt], 0, 0, 0);
        }
      }
      #pragma unroll
      for (int nt = 0; nt < 2; ++nt)
        #pragma unroll
        for (int jj = 0; jj < 4; ++jj)
          XA[wave*16 + 4*g + jj][h*32 + nt*16 + r] = f2b(o[nt][jj]);
    }
    __syncthreads();
  }

  // ---- proj GEMM + window-reverse + roll-back ----
  {
    f32x4 pacc[4][3];
    #pragma unroll
    for (int mt = 0; mt < 4; ++mt){ pacc[mt][0] = z4; pacc[mt][1] = z4; pacc[mt][2] = z4; }
    #pragma unroll
    for (int ks = 0; ks < 6; ++ks){
      bf16x8 a2[4];
      #pragma unroll
      for (int mt = 0; mt < 4; ++mt)
        a2[mt] = *reinterpret_cast<const bf16x8*>(&XA[mt*16 + r][ks*32 + 8*g]);
      #pragma unroll
      for (int nt = 0; nt < 3; ++nt){
        const bf16x8 bw = *reinterpret_cast<const bf16x8*>(wp + (size_t)(wave*48 + nt*16 + r)*192 + ks*32 + 8*g);
        #pragma unroll
        for (int mt = 0; mt < 4; ++mt)
          pacc[mt][nt] = __builtin_amdgcn_mfma_f32_16x16x32_bf16(a2[mt], bw, pacc[mt][nt], 0, 0, 0);
      }
    }
    #pragma unroll
    for (int nt = 0; nt < 3; ++nt){
      const int n = wave*48 + nt*16 + r;
      const float bias = pb[n];
      #pragma unroll
      for (int mt = 0; mt < 4; ++mt)
        #pragma unroll
        for (int jj = 0; jj < 4; ++jj){
          const int tok = mt*16 + 4*g + jj;
          if (tok < 49){
            const int ty = tok/7, tx = tok%7;
            int dh = wy*7 + ty + 3; if (dh >= 56) dh -= 56;
            int dw = wx*7 + tx + 3; if (dw >= 56) dw -= 56;
            out[(size_t)((bb*56 + dh)*56 + dw)*192 + n] = pacc[mt][nt][jj] + bias;
          }
        }
    }
  }
}

extern "C" void kernel_launch(void* const* d_in, const int* in_sizes, int n_in,
                              void* d_out, int out_size, void* d_ws, size_t ws_size,
                              hipStream_t stream) {
  const float* x     = (const float*)d_in[0];
  const float* rpb   = (const float*)d_in[1];
  const float* qkvw  = (const float*)d_in[2];
  const float* qkvb  = (const float*)d_in[3];
  const float* projw = (const float*)d_in[4];
  const float* projb = (const float*)d_in[5];
  float* out = (float*)d_out;

  char* ws = (char*)d_ws;
  u16* wq  = (u16*)(ws);            // bf16 [576][192]
  u16* wpj = (u16*)(ws + 221184);   // bf16 [192][192]

  prep_kernel <<<432, 256, 0, stream>>>(qkvw, projw, wq, wpj);
  fused_kernel<<<2048, 256, 0, stream>>>(x, wq, qkvb, wpj, projb, rpb, out);
}

// Round 4
// 169.671 us; speedup vs baseline: 1.2830x; 1.1739x over previous
//
#include <hip/hip_runtime.h>

typedef unsigned short u16;
typedef unsigned int   u32;
typedef __bf16 bf16x8 __attribute__((ext_vector_type(8)));
typedef float  f32x4  __attribute__((ext_vector_type(4)));

// Geometry (fixed): b=32, h=w=56, C=192, NH=6, hd=32, WS=7, shift=3
// 2048 windows, 49 tokens (padded to 64). One block (4 waves) per window.
// Per-head loop, LDS 48.5 KB -> 3 blocks/CU.

__device__ __forceinline__ u16 f2b(float f){            // RNE via HW cvt
  return __builtin_bit_cast(u16, (__bf16)f);
}
__device__ __forceinline__ u32 pk2(float a, float b){   // packs to v_cvt_pk_bf16_f32
  return (u32)f2b(a) | ((u32)f2b(b) << 16);
}

__global__ __launch_bounds__(256) void prep_kernel(const float* __restrict__ qkvw,
                                                   const float* __restrict__ projw,
                                                   u16* __restrict__ wq, u16* __restrict__ wp){
  const int i = blockIdx.x * 256 + threadIdx.x;
  if (i < 576*192) wq[i] = f2b(qkvw[i]);
  if (i < 192*192) wp[i] = f2b(projw[i]);
}

__device__ __forceinline__ int coords_fn(int t){ return (t/7)*13 + (t%7); }
__device__ __forceinline__ int code_fn(int t, int wy, int wx){
  const int ty = t/7, tx = t%7;
  const int hp = wy*7 + ty, wp = wx*7 + tx;
  const int rh = (hp < 49) ? 0 : ((hp < 53) ? 1 : 2);
  const int rw = (wp < 49) ? 0 : ((wp < 53) ? 1 : 2);
  return rh*3 + rw;
}

__global__ __launch_bounds__(256, 3) void fused_kernel(const float* __restrict__ x,
    const u16* __restrict__ wq, const float* __restrict__ qb,
    const u16* __restrict__ wp, const float* __restrict__ pb,
    const float* __restrict__ rpb, float* __restrict__ out)
{
  __shared__ u16 XA[64][200];    // phase 1: x tile; later: AO overlay
  __shared__ u16 qsh[64][40];    // per-head q [tok][32+8]
  __shared__ u16 ksh[64][40];    // per-head k [tok][32+8]
  __shared__ u16 vTsh[32][72];   // per-head v^T [d][tok+8]
  __shared__ u16 Ps[4][16][72];  // per-wave P [qrow][j], natural layout

  const int wi = blockIdx.x;
  const int bb = wi >> 6, wy = (wi >> 3) & 7, wx = wi & 7;
  const int tid = threadIdx.x;
  const int wave = tid >> 6, lane = tid & 63;
  const int g = lane >> 4, r = lane & 15;
  const int wm = wave >> 1, wn = wave & 1;   // QKV GEMM: 2x2 wave grid
  const f32x4 z4 = {0.f, 0.f, 0.f, 0.f};

  // ---- phase 1: roll + window gather, fp32 -> bf16, rows >=49 zeroed ----
  for (int it = tid; it < 64*48; it += 256){
    const int row = it / 48, c4 = (it % 48) * 4;
    u32 p0 = 0, p1 = 0;
    if (row < 49){
      const int ty = row / 7, tx = row % 7;
      int sh = wy*7 + ty + 3; if (sh >= 56) sh -= 56;
      int sw = wx*7 + tx + 3; if (sw >= 56) sw -= 56;
      const float4 f = *reinterpret_cast<const float4*>(x + (size_t)(((bb*56 + sh)*56 + sw))*192 + c4);
      p0 = pk2(f.x, f.y);
      p1 = pk2(f.z, f.w);
    }
    u32* dst = reinterpret_cast<u32*>(&XA[row][c4]);
    dst[0] = p0; dst[1] = p1;
  }
  __syncthreads();

  // ---- hoist X fragments: rows wm*32 + mt*16 + r ----
  bf16x8 af[6][2];
  #pragma unroll
  for (int ks = 0; ks < 6; ++ks)
    #pragma unroll
    for (int mt = 0; mt < 2; ++mt)
      af[ks][mt] = *reinterpret_cast<const bf16x8*>(&XA[wm*32 + mt*16 + r][ks*32 + 8*g]);

  // ---- attention metadata (h-independent), swapped-layout: lane query i = wave*16+r ----
  const int i_r = wave*16 + r;
  const int icl = (i_r > 48) ? 48 : i_r;
  const int ci_r = coords_fn(icl);
  const int codei_r = code_fn(icl, wy, wx);
  int   idx[4][4];     // (ci_r + cj)*6 for j = 16mt + 4g + jj
  float maskM[4][4];   // 0 / -100 / -1e30
  #pragma unroll
  for (int mt = 0; mt < 4; ++mt)
    #pragma unroll
    for (int jj = 0; jj < 4; ++jj){
      const int j = 16*mt + 4*g + jj;
      const bool jv = (j < 49);
      const int jc = jv ? (48 - j) : 0;
      idx[mt][jj] = (ci_r + coords_fn(jc)) * 6;
      maskM[mt][jj] = jv ? ((codei_r == code_fn(j, wy, wx)) ? 0.f : -100.f) : -1e30f;
    }

  // ---- per-head loop ----
  #pragma unroll 1
  for (int h = 0; h < 6; ++h){
    // QKV GEMM for head h: out 64x96 (q|k|v), wave (wm,wn)
    f32x4 acc[2][3];
    float biasv[3];
    #pragma unroll
    for (int mt = 0; mt < 2; ++mt)
      #pragma unroll
      for (int nt = 0; nt < 3; ++nt)
        acc[mt][nt] = z4;
    #pragma unroll
    for (int nt = 0; nt < 3; ++nt){
      const int base = wn*48 + nt*16;        // {0,16,32} or {48,64,80}
      const int seg = base >> 5;             // 0=q 1=k 2=v
      const int wrow = seg*192 + h*32 + (base - seg*32) + r;
      bf16x8 bf_[6];
      #pragma unroll
      for (int ks = 0; ks < 6; ++ks)
        bf_[ks] = *reinterpret_cast<const bf16x8*>(wq + (size_t)wrow*192 + ks*32 + 8*g);
      biasv[nt] = qb[wrow];
      #pragma unroll
      for (int ks = 0; ks < 6; ++ks)
        #pragma unroll
        for (int mt = 0; mt < 2; ++mt)
          acc[mt][nt] = __builtin_amdgcn_mfma_f32_16x16x32_bf16(af[ks][mt], bf_[ks], acc[mt][nt], 0, 0, 0);
    }
    // epilogue: q,k natural (b16 scatter); v transposed (packed b64)
    #pragma unroll
    for (int nt = 0; nt < 3; ++nt){
      const int base = wn*48 + nt*16;
      const int seg = base >> 5;
      if (seg == 0){
        #pragma unroll
        for (int mt = 0; mt < 2; ++mt)
          #pragma unroll
          for (int jj = 0; jj < 4; ++jj)
            qsh[wm*32 + mt*16 + 4*g + jj][base + r] =
              f2b((acc[mt][nt][jj] + biasv[nt]) * 0.17677669529663687f);
      } else if (seg == 1){
        #pragma unroll
        for (int mt = 0; mt < 2; ++mt)
          #pragma unroll
          for (int jj = 0; jj < 4; ++jj)
            ksh[wm*32 + mt*16 + 4*g + jj][base - 32 + r] = f2b(acc[mt][nt][jj] + biasv[nt]);
      } else {
        const int d = base - 64 + r;
        #pragma unroll
        for (int mt = 0; mt < 2; ++mt){
          uint2 pv;
          pv.x = pk2(acc[mt][nt][0] + biasv[nt], acc[mt][nt][1] + biasv[nt]);
          pv.y = pk2(acc[mt][nt][2] + biasv[nt], acc[mt][nt][3] + biasv[nt]);
          *reinterpret_cast<uint2*>(&vTsh[d][wm*32 + mt*16 + 4*g]) = pv;
        }
      }
    }
    __syncthreads();

    // ---- attention head h (swapped QK^T: lane holds row i=r, 16 in-lane j) ----
    {
      // rpb prefetch (L1-resident table), issued before MFMAs
      float rv[4][4];
      #pragma unroll
      for (int mt = 0; mt < 4; ++mt)
        #pragma unroll
        for (int jj = 0; jj < 4; ++jj)
          rv[mt][jj] = rpb[idx[mt][jj] + h];

      const bf16x8 aq = *reinterpret_cast<const bf16x8*>(&qsh[wave*16 + r][8*g]);
      f32x4 s[4];
      #pragma unroll
      for (int mt = 0; mt < 4; ++mt){
        const bf16x8 bk = *reinterpret_cast<const bf16x8*>(&ksh[mt*16 + r][8*g]);
        s[mt] = __builtin_amdgcn_mfma_f32_16x16x32_bf16(bk, aq, z4, 0, 0, 0);  // S^T
      }
      // bias + mask + in-lane max over 16 j
      float mx = -1e30f;
      #pragma unroll
      for (int mt = 0; mt < 4; ++mt)
        #pragma unroll
        for (int jj = 0; jj < 4; ++jj){
          const float t = s[mt][jj] + rv[mt][jj] + maskM[mt][jj];
          s[mt][jj] = t;
          mx = fmaxf(mx, t);
        }
      mx = fmaxf(mx, __shfl_xor(mx, 16));
      mx = fmaxf(mx, __shfl_xor(mx, 32));
      float sum = 0.f;
      #pragma unroll
      for (int mt = 0; mt < 4; ++mt)
        #pragma unroll
        for (int jj = 0; jj < 4; ++jj){
          const float p = __expf(s[mt][jj] - mx);
          s[mt][jj] = p;
          sum += p;
        }
      sum += __shfl_xor(sum, 16);
      sum += __shfl_xor(sum, 32);
      const float rs = 1.0f / sum;
      // P natural [i][j]: 4x b64 contiguous writes
      #pragma unroll
      for (int mt = 0; mt < 4; ++mt){
        uint2 pw;
        pw.x = pk2(s[mt][0]*rs, s[mt][1]*rs);
        pw.y = pk2(s[mt][2]*rs, s[mt][3]*rs);
        *reinterpret_cast<uint2*>(&Ps[wave][r][16*mt + 4*g]) = pw;
      }
      // PV swapped: C[d][i] -> lane holds O[tok=w16+r][4 consecutive ch]
      f32x4 o[2] = {z4, z4};
      #pragma unroll
      for (int k2 = 0; k2 < 2; ++k2){
        const bf16x8 ap = *reinterpret_cast<const bf16x8*>(&Ps[wave][r][32*k2 + 8*g]);
        #pragma unroll
        for (int nt = 0; nt < 2; ++nt){
          const bf16x8 bv = *reinterpret_cast<const bf16x8*>(&vTsh[16*nt + r][32*k2 + 8*g]);
          o[nt] = __builtin_amdgcn_mfma_f32_16x16x32_bf16(bv, ap, o[nt], 0, 0, 0);
        }
      }
      #pragma unroll
      for (int nt = 0; nt < 2; ++nt){
        uint2 ow;
        ow.x = pk2(o[nt][0], o[nt][1]);
        ow.y = pk2(o[nt][2], o[nt][3]);
        *reinterpret_cast<uint2*>(&XA[wave*16 + r][h*32 + 16*nt + 4*g]) = ow;
      }
    }
    __syncthreads();
  }

  // ---- proj GEMM + window-reverse + roll-back ----
  {
    f32x4 pacc[4][3];
    #pragma unroll
    for (int mt = 0; mt < 4; ++mt){ pacc[mt][0] = z4; pacc[mt][1] = z4; pacc[mt][2] = z4; }
    #pragma unroll
    for (int ks = 0; ks < 6; ++ks){
      bf16x8 a2[4];
      #pragma unroll
      for (int mt = 0; mt < 4; ++mt)
        a2[mt] = *reinterpret_cast<const bf16x8*>(&XA[mt*16 + r][ks*32 + 8*g]);
      #pragma unroll
      for (int nt = 0; nt < 3; ++nt){
        const bf16x8 bw = *reinterpret_cast<const bf16x8*>(wp + (size_t)(wave*48 + nt*16 + r)*192 + ks*32 + 8*g);
        #pragma unroll
        for (int mt = 0; mt < 4; ++mt)
          pacc[mt][nt] = __builtin_amdgcn_mfma_f32_16x16x32_bf16(a2[mt], bw, pacc[mt][nt], 0, 0, 0);
      }
    }
    #pragma unroll
    for (int nt = 0; nt < 3; ++nt){
      const int n = wave*48 + nt*16 + r;
      const float bias = pb[n];
      #pragma unroll
      for (int mt = 0; mt < 4; ++mt)
        #pragma unroll
        for (int jj = 0; jj < 4; ++jj){
          const int tok = mt*16 + 4*g + jj;
          if (tok < 49){
            const int ty = tok/7, tx = tok%7;
            int dh = wy*7 + ty + 3; if (dh >= 56) dh -= 56;
            int dw = wx*7 + tx + 3; if (dw >= 56) dw -= 56;
            out[(size_t)((bb*56 + dh)*56 + dw)*192 + n] = pacc[mt][nt][jj] + bias;
          }
        }
    }
  }
}

extern "C" void kernel_launch(void* const* d_in, const int* in_sizes, int n_in,
                              void* d_out, int out_size, void* d_ws, size_t ws_size,
                              hipStream_t stream) {
  const float* x     = (const float*)d_in[0];
  const float* rpb   = (const float*)d_in[1];
  const float* qkvw  = (const float*)d_in[2];
  const float* qkvb  = (const float*)d_in[3];
  const float* projw = (const float*)d_in[4];
  const float* projb = (const float*)d_in[5];
  float* out = (float*)d_out;

  char* ws = (char*)d_ws;
  u16* wq  = (u16*)(ws);            // bf16 [576][192]
  u16* wpj = (u16*)(ws + 221184);   // bf16 [192][192]

  prep_kernel <<<432, 256, 0, stream>>>(qkvw, projw, wq, wpj);
  fused_kernel<<<2048, 256, 0, stream>>>(x, wq, qkvb, wpj, projb, rpb, out);
}